// Round 1
// baseline (1271.369 us; speedup 1.0000x reference)
//
#include <hip/hip_runtime.h>
#include <hip/hip_bf16.h>

typedef _Float16 f16;
typedef _Float16 f16x8 __attribute__((ext_vector_type(8)));
typedef float f32x4 __attribute__((ext_vector_type(4)));

#define NB 8
#define NC 192
#define NC3 576
#define NS 16384
#define NHD 4

// ---- workspace offsets (bytes). total ~338 MB ----
#define OFF_X16   (0ll)
#define OFF_CN16  (50331648ll)     // reused as qkv1 part buffer after kernel A
#define OFF_CN1   (100663296ll)
#define OFF_CNF   (150994944ll)
#define OFF_QKVD  (201326592ll)
#define OFF_NORMS (352321536ll)
#define OFF_G1    (352346112ll)
#define OFF_G2    (352641024ll)
#define OFF_ZPAD  (352935936ll)
#define OFF_ATTN  (352936960ll)
#define OFF_W116  (353231872ll)
#define OFF_WQ16  (353305600ll)
#define OFF_W3P   (353526784ll)
#define OFF_MCOMB (354190336ll)

__device__ __forceinline__ void async16(const void* g, void* l) {
  __builtin_amdgcn_global_load_lds(
      (const __attribute__((address_space(1))) unsigned int*)g,
      (__attribute__((address_space(3))) unsigned int*)l, 16, 0, 0);
}
#define MFMA(a,b,c) __builtin_amdgcn_mfma_f32_16x16x32_f16((a),(b),(c),0,0,0)

// ---------------------------------------------------------------------------
// P2: cast/pack all weights to f16. w3 repacked [tap][co][ci].
__global__ void k_wcast(const float* __restrict__ w1, const float* __restrict__ wq,
                        const float* __restrict__ w3,
                        f16* __restrict__ w1o, f16* __restrict__ wqo, f16* __restrict__ w3p)
{
  int idx = blockIdx.x * 256 + threadIdx.x;              // 479232 total
  if (idx < 36864) {
    w1o[idx] = (f16)w1[idx];
  } else if (idx < 147456) {
    int i = idx - 36864;
    wqo[i] = (f16)wq[i];
  } else {
    int i = idx - 147456;
    int tap = i / 36864;
    int rem = i % 36864;                                 // co*192+ci
    w3p[i] = (f16)w3[(size_t)rem * 9 + tap];
  }
}

// ---------------------------------------------------------------------------
// P1: transpose-cast x,cn : fp32 [b][c][s] -> f16 [b][s][c]
__global__ __launch_bounds__(256)
void k_cast_t(const float* __restrict__ xin, const float* __restrict__ cnin,
              f16* __restrict__ xo, f16* __restrict__ cno)
{
  __shared__ f16 tile[64 * 66];
  int b = blockIdx.z & 7;
  const float* in = (blockIdx.z >= 8) ? cnin : xin;
  f16* out = (blockIdx.z >= 8) ? cno : xo;
  int s0 = blockIdx.x * 64, c0 = blockIdx.y * 64;
  int t = threadIdx.x;
  int sl = t & 63, cq = t >> 6;
#pragma unroll
  for (int r = 0; r < 16; ++r) {
    int cl = r * 4 + cq;
    float v = in[((size_t)b * NC + c0 + cl) * NS + s0 + sl];
    tile[cl * 66 + sl] = (f16)v;
  }
  __syncthreads();
  int cl2 = t & 63, sq = t >> 6;
#pragma unroll
  for (int r = 0; r < 16; ++r) {
    int sl2 = r * 4 + sq;
    out[((size_t)b * NS + s0 + sl2) * NC + c0 + cl2] = tile[cl2 * 66 + sl2];
  }
}

// ---------------------------------------------------------------------------
// BT-GEMM: out[b][s][co] = sum_ci act[b][s][ci] * wt[co][ci]. M=s tile 256, N=co 64, K=192.
// chunk rotation by (row>>2)&3 spreads ds_read_b128 banks (2-way = free).
__global__ __launch_bounds__(256, 2)
void k_gemm_act(const f16* __restrict__ act, const f16* __restrict__ wt,
                f16* __restrict__ out)
{
  __shared__ f16 At[256 * 32];
  __shared__ f16 Bt[64 * 32];
  const int tid = threadIdx.x;
  const int b = blockIdx.z;
  const int s0 = blockIdx.x * 256;
  const int n0 = blockIdx.y * 64;
  const int w = tid >> 6, lane = tid & 63, quad = lane >> 4, l16 = lane & 15;
  const f16* actB = act + (size_t)b * NS * NC;

  const f32x4 Z = {0.f, 0.f, 0.f, 0.f};
  f32x4 acc[4][4];
#pragma unroll
  for (int i = 0; i < 4; ++i)
#pragma unroll
    for (int j = 0; j < 4; ++j) acc[i][j] = Z;

  for (int kc = 0; kc < 6; ++kc) {
    const int k0 = kc * 32;
#pragma unroll
    for (int i = 0; i < 4; ++i) {
      int r = i * 64 + (w << 4) + (lane >> 2);
      int col = k0 + ((((lane & 3) + (r >> 2)) & 3) << 3);
      async16(actB + (size_t)(s0 + r) * NC + col, At + (size_t)(i * 64 + (w << 4)) * 32);
    }
    {
      int rb = (w << 4) + (lane >> 2);
      int colb = k0 + ((((lane & 3) + (rb >> 2)) & 3) << 3);
      async16(wt + (size_t)(n0 + rb) * NC + colb, Bt + (size_t)(w << 4) * 32);
    }
    __syncthreads();

    f16x8 bf[4];
#pragma unroll
    for (int nt = 0; nt < 4; ++nt) {
      int n = nt * 16 + l16;
      int p = (quad - (n >> 2)) & 3;
      bf[nt] = *(const f16x8*)(Bt + n * 32 + p * 8);
    }
#pragma unroll
    for (int mt = 0; mt < 4; ++mt) {
      int m = w * 64 + mt * 16 + l16;
      int p = (quad - (m >> 2)) & 3;
      f16x8 af = *(const f16x8*)(At + m * 32 + p * 8);
#pragma unroll
      for (int nt = 0; nt < 4; ++nt) acc[mt][nt] = MFMA(af, bf[nt], acc[mt][nt]);
    }
    __syncthreads();
  }
  // epilogue: D row = s, col = co
#pragma unroll
  for (int mt = 0; mt < 4; ++mt)
#pragma unroll
    for (int r = 0; r < 4; ++r) {
      int sg = s0 + w * 64 + mt * 16 + quad * 4 + r;
      f16* o = out + ((size_t)b * NS + sg) * NC + n0;
#pragma unroll
      for (int nt = 0; nt < 4; ++nt) o[nt * 16 + l16] = (f16)acc[mt][nt][r];
    }
}

// ---------------------------------------------------------------------------
// conv3x3 implicit GEMM: out[b][s][co] = sum_tap sum_ci act[b][s+off][ci]*w3p[tap][co][ci]
__global__ __launch_bounds__(256, 2)
void k_conv3(const f16* __restrict__ act, const f16* __restrict__ w3p,
             f16* __restrict__ out, const f16* __restrict__ zpad)
{
  __shared__ f16 At[256 * 32];
  __shared__ f16 Bt[64 * 32];
  const int tid = threadIdx.x;
  const int b = blockIdx.z;
  const int s0 = blockIdx.x * 256;
  const int n0 = blockIdx.y * 64;
  const int w = tid >> 6, lane = tid & 63, quad = lane >> 4, l16 = lane & 15;
  const f16* actB = act + (size_t)b * NS * NC;

  const f32x4 Z = {0.f, 0.f, 0.f, 0.f};
  f32x4 acc[4][4];
#pragma unroll
  for (int i = 0; i < 4; ++i)
#pragma unroll
    for (int j = 0; j < 4; ++j) acc[i][j] = Z;

  for (int tap = 0; tap < 9; ++tap) {
    const int dy = tap / 3 - 1, dx = tap % 3 - 1;
    const int off = dy * 128 + dx;
    const f16* wt = w3p + (size_t)tap * NC * NC;
    for (int kc = 0; kc < 6; ++kc) {
      const int k0 = kc * 32;
#pragma unroll
      for (int i = 0; i < 4; ++i) {
        int r = i * 64 + (w << 4) + (lane >> 2);
        int sg = s0 + r;
        int x = sg & 127, y = sg >> 7;
        bool valid = ((unsigned)(x + dx) < 128u) && ((unsigned)(y + dy) < 128u);
        int col = k0 + ((((lane & 3) + (r >> 2)) & 3) << 3);
        const f16* g = valid ? (actB + (size_t)(sg + off) * NC + col) : zpad;
        async16(g, At + (size_t)(i * 64 + (w << 4)) * 32);
      }
      {
        int rb = (w << 4) + (lane >> 2);
        int colb = k0 + ((((lane & 3) + (rb >> 2)) & 3) << 3);
        async16(wt + (size_t)(n0 + rb) * NC + colb, Bt + (size_t)(w << 4) * 32);
      }
      __syncthreads();
      f16x8 bf[4];
#pragma unroll
      for (int nt = 0; nt < 4; ++nt) {
        int n = nt * 16 + l16;
        int p = (quad - (n >> 2)) & 3;
        bf[nt] = *(const f16x8*)(Bt + n * 32 + p * 8);
      }
#pragma unroll
      for (int mt = 0; mt < 4; ++mt) {
        int m = w * 64 + mt * 16 + l16;
        int p = (quad - (m >> 2)) & 3;
        f16x8 af = *(const f16x8*)(At + m * 32 + p * 8);
#pragma unroll
        for (int nt = 0; nt < 4; ++nt) acc[mt][nt] = MFMA(af, bf[nt], acc[mt][nt]);
      }
      __syncthreads();
    }
  }
#pragma unroll
  for (int mt = 0; mt < 4; ++mt)
#pragma unroll
    for (int r = 0; r < 4; ++r) {
      int sg = s0 + w * 64 + mt * 16 + quad * 4 + r;
      f16* o = out + ((size_t)b * NS + sg) * NC + n0;
#pragma unroll
      for (int nt = 0; nt < 4; ++nt) o[nt * 16 + l16] = (f16)acc[mt][nt][r];
    }
}

// ---------------------------------------------------------------------------
// depthwise 3x3 on one 192-channel part: in [b][s][192] -> out [b][s][576] at col part*192
__global__ __launch_bounds__(256)
void k_dw(const f16* __restrict__ in, const float* __restrict__ wdw,
          f16* __restrict__ out, int part)
{
  int idx = blockIdx.x * 256 + threadIdx.x;   // exact 25165824
  int c = idx % NC;
  int s = (idx / NC) % NS;
  int b = idx / (NC * NS);
  int x = s & 127, y = s >> 7;
  const float* wp = wdw + (size_t)(part * NC + c) * 9;
  const f16* ip = in + ((size_t)b * NS + s) * NC + c;
  float a = 0.f;
#pragma unroll
  for (int t = 0; t < 9; ++t) {
    int dy = t / 3 - 1, dx = t % 3 - 1;
    if (((unsigned)(x + dx) < 128u) && ((unsigned)(y + dy) < 128u))
      a += wp[t] * (float)ip[(dy * 128 + dx) * NC];
  }
  out[((size_t)b * NS + s) * NC3 + part * NC + c] = (f16)a;
}

// ---------------------------------------------------------------------------
// E1: per (b,c): sum q^2, k^2, cn^2, q*cn over spatial. 192 threads (=3 waves), c=tid.
__global__ void k_e1(const f16* __restrict__ qkvd, const f16* __restrict__ cnf,
                     float* __restrict__ norms)
{
  int blk = blockIdx.x;
  int b = blk >> 5;
  int chunk = blk & 31;
  int c = threadIdx.x;
  float q2 = 0, k2 = 0, cn2 = 0, qc = 0;
  int sBase = chunk * 512;
  const f16* qp = qkvd + ((size_t)b * NS + sBase) * NC3;
  const f16* cp = cnf + ((size_t)b * NS + sBase) * NC;
  for (int s = 0; s < 512; ++s) {
    float q = (float)qp[(size_t)s * NC3 + c];
    float k = (float)qp[(size_t)s * NC3 + 192 + c];
    float n = (float)cp[(size_t)s * NC + c];
    q2 += q * q; k2 += k * k; cn2 += n * n; qc += q * n;
  }
  float* np = norms + ((size_t)b * NC + c) * 4;
  atomicAdd(np + 0, q2); atomicAdd(np + 1, k2);
  atomicAdd(np + 2, cn2); atomicAdd(np + 3, qc);
}

// ---------------------------------------------------------------------------
// E2: G1[b,h,c,d]=sum_s q*k ; G2=sum_s cn*k. 1 wave/block, LDS transpose staging + MFMA.
__global__ __launch_bounds__(64)
void k_e2(const f16* __restrict__ qkvd, const f16* __restrict__ cnf,
          float* __restrict__ G1, float* __restrict__ G2)
{
  __shared__ f16 qT[48 * 72];
  __shared__ f16 kT[48 * 72];
  __shared__ f16 cT[48 * 72];
  int blk = blockIdx.x;               // b(8) x h(4) x split(16)
  int split = blk & 15;
  int h = (blk >> 4) & 3;
  int b = blk >> 6;
  int lane = threadIdx.x, quad = lane >> 4, l16 = lane & 15;
  const f32x4 Z = {0.f, 0.f, 0.f, 0.f};
  f32x4 g1[3][3], g2[3][3];
#pragma unroll
  for (int i = 0; i < 3; ++i)
#pragma unroll
    for (int j = 0; j < 3; ++j) { g1[i][j] = Z; g2[i][j] = Z; }

  int sBase = split * 1024;
  for (int chunk = 0; chunk < 16; ++chunk) {
    int sb = sBase + chunk * 64;
    __syncthreads();
#pragma unroll
    for (int it = 0; it < 24; ++it) {
      int idx = it * 64 + lane;       // 1536 = 64 rows x 24 u32
      int r = idx / 24;
      int cw = idx % 24;
      const f16* qrow = qkvd + ((size_t)b * NS + sb + r) * NC3 + h * 48;
      const f16* crow = cnf + ((size_t)b * NS + sb + r) * NC + h * 48;
      unsigned qv = *(const unsigned*)(qrow + cw * 2);
      unsigned kv = *(const unsigned*)(qrow + 192 + cw * 2);
      unsigned nv = *(const unsigned*)(crow + cw * 2);
      qT[(cw * 2) * 72 + r] = ((const f16*)&qv)[0];
      qT[(cw * 2 + 1) * 72 + r] = ((const f16*)&qv)[1];
      kT[(cw * 2) * 72 + r] = ((const f16*)&kv)[0];
      kT[(cw * 2 + 1) * 72 + r] = ((const f16*)&kv)[1];
      cT[(cw * 2) * 72 + r] = ((const f16*)&nv)[0];
      cT[(cw * 2 + 1) * 72 + r] = ((const f16*)&nv)[1];
    }
    __syncthreads();
#pragma unroll
    for (int kk = 0; kk < 2; ++kk) {
      int ko = kk * 32 + quad * 8;
      f16x8 bfr[3];
#pragma unroll
      for (int dt = 0; dt < 3; ++dt) bfr[dt] = *(const f16x8*)(kT + (dt * 16 + l16) * 72 + ko);
#pragma unroll
      for (int ct = 0; ct < 3; ++ct) {
        f16x8 aq = *(const f16x8*)(qT + (ct * 16 + l16) * 72 + ko);
        f16x8 an = *(const f16x8*)(cT + (ct * 16 + l16) * 72 + ko);
#pragma unroll
        for (int dt = 0; dt < 3; ++dt) {
          g1[ct][dt] = MFMA(aq, bfr[dt], g1[ct][dt]);
          g2[ct][dt] = MFMA(an, bfr[dt], g2[ct][dt]);
        }
      }
    }
  }
#pragma unroll
  for (int ct = 0; ct < 3; ++ct)
#pragma unroll
    for (int dt = 0; dt < 3; ++dt)
#pragma unroll
      for (int r = 0; r < 4; ++r) {
        int c = ct * 16 + quad * 4 + r;
        int d = dt * 16 + l16;
        size_t o = (((size_t)(b * NHD + h) * 48 + c) * 48 + d);
        atomicAdd(G1 + o, g1[ct][dt][r]);
        atomicAdd(G2 + o, g2[ct][dt][r]);
      }
}

// ---------------------------------------------------------------------------
// F1: logits + softmax -> attn[b][h][c][d] (fp32)
__global__ __launch_bounds__(64)
void k_f1(const float* __restrict__ G1, const float* __restrict__ G2,
          const float* __restrict__ norms, const float* __restrict__ temp,
          float* __restrict__ attn)
{
  __shared__ float S[48 * 48];
  int h = blockIdx.x & 3, b = blockIdx.x >> 2;
  int t = threadIdx.x;
  float T = temp[h];
  const float EPS = 1e-12f;
#pragma unroll
  for (int i = 0; i < 36; ++i) {
    int idx = i * 64 + t;
    int c = idx / 48, d = idx % 48;
    const float* np = norms + ((size_t)b * NC + h * 48 + c) * 4;
    float q2 = np[0], cn2 = np[2], qc = np[3];
    float nq = fmaxf(sqrtf(q2), EPS);
    float ncn = fmaxf(sqrtf(cn2), EPS);
    float k2 = norms[((size_t)b * NC + h * 48 + d) * 4 + 1];
    float nk = fmaxf(sqrtf(k2), EPS);
    float ss = q2 / (nq * nq) + 2.f * qc / (nq * ncn) + cn2 / (ncn * ncn);
    float nsum = fmaxf(sqrtf(fmaxf(ss, 0.f)), EPS);
    size_t go = (((size_t)(b * NHD + h) * 48 + c) * 48 + d);
    S[idx] = (G1[go] / nq + G2[go] / ncn) / (nsum * nk) * T;
  }
  __syncthreads();
  if (t < 48) {
    float mx = -1e30f;
    for (int d = 0; d < 48; ++d) mx = fmaxf(mx, S[t * 48 + d]);
    float sum = 0.f;
    for (int d = 0; d < 48; ++d) { float e = expf(S[t * 48 + d] - mx); S[t * 48 + d] = e; sum += e; }
    float inv = 1.f / sum;
    float* ap = attn + (((size_t)(b * NHD + h) * 48 + t) * 48);
    for (int d = 0; d < 48; ++d) ap[d] = S[t * 48 + d] * inv;
  }
}

// ---------------------------------------------------------------------------
// F2: Mcomb[b][co][dg] = sum_cl projw[co][h*48+cl] * attn[b][h][cl][dg%48]  (f16 out)
__global__ void k_f2(const float* __restrict__ attn, const float* __restrict__ projw,
                     f16* __restrict__ mcomb)
{
  int idx = blockIdx.x * 256 + threadIdx.x;   // 294912 exact
  int dg = idx % NC;
  int co = (idx / NC) % NC;
  int b = idx / (NC * NC);
  int h = dg / 48, dl = dg % 48;
  const float* pw = projw + (size_t)co * NC + h * 48;
  const float* at = attn + ((size_t)(b * NHD + h) * 48) * 48 + dl;
  float a = 0.f;
#pragma unroll
  for (int cl = 0; cl < 48; ++cl) a += pw[cl] * at[cl * 48];
  mcomb[idx] = (f16)a;
}

// ---------------------------------------------------------------------------
// G: out[b][co][s] = sum_dg mcomb[b][co][dg] * v[b][s][dg]  (v = qkvd cols 384..575), fp32 out
__global__ __launch_bounds__(256, 2)
void k_gemm_out(const f16* __restrict__ mcomb, const f16* __restrict__ qkvd,
                float* __restrict__ out)
{
  __shared__ f16 At[64 * 32];
  __shared__ f16 Bt[256 * 32];
  const int tid = threadIdx.x;
  const int b = blockIdx.z;
  const int s0 = blockIdx.x * 256;
  const int m0 = blockIdx.y * 64;
  const int w = tid >> 6, lane = tid & 63, quad = lane >> 4, l16 = lane & 15;
  const f16* mcB = mcomb + (size_t)b * NC * NC;
  const f16* vB = qkvd + (size_t)b * NS * NC3 + 384;

  const f32x4 Z = {0.f, 0.f, 0.f, 0.f};
  f32x4 acc[4][4];
#pragma unroll
  for (int i = 0; i < 4; ++i)
#pragma unroll
    for (int j = 0; j < 4; ++j) acc[i][j] = Z;

  for (int kc = 0; kc < 6; ++kc) {
    const int k0 = kc * 32;
    {
      int rb = (w << 4) + (lane >> 2);
      int colb = k0 + ((((lane & 3) + (rb >> 2)) & 3) << 3);
      async16(mcB + (size_t)(m0 + rb) * NC + colb, At + (size_t)(w << 4) * 32);
    }
#pragma unroll
    for (int i = 0; i < 4; ++i) {
      int r = i * 64 + (w << 4) + (lane >> 2);
      int col = k0 + ((((lane & 3) + (r >> 2)) & 3) << 3);
      async16(vB + (size_t)(s0 + r) * NC3 + col, Bt + (size_t)(i * 64 + (w << 4)) * 32);
    }
    __syncthreads();
    f16x8 af[4];
#pragma unroll
    for (int mt = 0; mt < 4; ++mt) {
      int m = mt * 16 + l16;
      int p = (quad - (m >> 2)) & 3;
      af[mt] = *(const f16x8*)(At + m * 32 + p * 8);
    }
#pragma unroll
    for (int nt = 0; nt < 4; ++nt) {
      int n = w * 64 + nt * 16 + l16;
      int p = (quad - (n >> 2)) & 3;
      f16x8 bf = *(const f16x8*)(Bt + n * 32 + p * 8);
#pragma unroll
      for (int mt = 0; mt < 4; ++mt) acc[mt][nt] = MFMA(af[mt], bf, acc[mt][nt]);
    }
    __syncthreads();
  }
  // D row = co, col = s
#pragma unroll
  for (int mt = 0; mt < 4; ++mt)
#pragma unroll
    for (int r = 0; r < 4; ++r) {
      int cog = m0 + mt * 16 + quad * 4 + r;
      float* o = out + ((size_t)b * NC + cog) * NS + s0 + w * 64;
#pragma unroll
      for (int nt = 0; nt < 4; ++nt) o[nt * 16 + l16] = acc[mt][nt][r];
    }
}

// ---------------------------------------------------------------------------
extern "C" void kernel_launch(void* const* d_in, const int* in_sizes, int n_in,
                              void* d_out, int out_size, void* d_ws, size_t ws_size,
                              hipStream_t stream) {
  const float* x   = (const float*)d_in[0];
  const float* cn  = (const float*)d_in[1];
  const float* w1  = (const float*)d_in[2];
  const float* w3  = (const float*)d_in[3];
  const float* wq  = (const float*)d_in[4];
  const float* wdw = (const float*)d_in[5];
  const float* wpj = (const float*)d_in[6];
  const float* tmp = (const float*)d_in[7];
  float* out = (float*)d_out;
  char* ws = (char*)d_ws;

  f16* x16    = (f16*)(ws + OFF_X16);
  f16* cn16   = (f16*)(ws + OFF_CN16);
  f16* qkv1p  = (f16*)(ws + OFF_CN16);   // overlay: cn16 dead after kernel A
  f16* cn1    = (f16*)(ws + OFF_CN1);
  f16* cnf    = (f16*)(ws + OFF_CNF);
  f16* qkvd   = (f16*)(ws + OFF_QKVD);
  float* norms = (float*)(ws + OFF_NORMS);
  float* G1    = (float*)(ws + OFF_G1);
  float* G2    = (float*)(ws + OFF_G2);
  f16* zpad   = (f16*)(ws + OFF_ZPAD);
  float* attn  = (float*)(ws + OFF_ATTN);
  f16* w116   = (f16*)(ws + OFF_W116);
  f16* wq16   = (f16*)(ws + OFF_WQ16);
  f16* w3p    = (f16*)(ws + OFF_W3P);
  f16* mcomb  = (f16*)(ws + OFF_MCOMB);

  // zero accumulators (norms, G1, G2) + zero page
  hipMemsetAsync(ws + OFF_NORMS, 0, 615424, stream);

  k_wcast<<<1872, 256, 0, stream>>>(w1, wq, w3, w116, wq16, w3p);
  k_cast_t<<<dim3(256, 3, 16), 256, 0, stream>>>(x, cn, x16, cn16);
  k_gemm_act<<<dim3(64, 3, 8), 256, 0, stream>>>(cn16, w116, cn1);
  k_conv3<<<dim3(64, 3, 8), 256, 0, stream>>>(cn1, w3p, cnf, zpad);
  for (int p = 0; p < 3; ++p) {
    k_gemm_act<<<dim3(64, 3, 8), 256, 0, stream>>>(x16, wq16 + p * 36864, qkv1p);
    k_dw<<<98304, 256, 0, stream>>>(qkv1p, wdw, qkvd, p);
  }
  k_e1<<<256, 192, 0, stream>>>(qkvd, cnf, norms);
  k_e2<<<512, 64, 0, stream>>>(qkvd, cnf, G1, G2);
  k_f1<<<32, 64, 0, stream>>>(G1, G2, norms, tmp, attn);
  k_f2<<<1152, 256, 0, stream>>>(attn, wpj, mcomb);
  k_gemm_out<<<dim3(64, 3, 8), 256, 0, stream>>>(mcomb, qkvd, out);

  (void)in_sizes; (void)n_in; (void)out_size; (void)ws_size;
}

// Round 2
// 1059.803 us; speedup vs baseline: 1.1996x; 1.1996x over previous
//
#include <hip/hip_runtime.h>
#include <hip/hip_bf16.h>

typedef _Float16 f16;
typedef _Float16 f16x8 __attribute__((ext_vector_type(8)));
typedef float f32x4 __attribute__((ext_vector_type(4)));

#define NB 8
#define NC 192
#define NC3 576
#define NS 16384
#define NHD 4

// ---- workspace offsets (bytes). total ~355 MB ----
#define OFF_X16   (0ll)
#define OFF_CN16  (50331648ll)     // reused as qkv1 part buffer after kernel A
#define OFF_CN1   (100663296ll)
#define OFF_CNF   (150994944ll)
#define OFF_QKVD  (201326592ll)
#define OFF_NORMS (352321536ll)
#define OFF_G1    (352346112ll)
#define OFF_G2    (352641024ll)
#define OFF_ZPAD  (352935936ll)
#define OFF_ATTN  (352936960ll)
#define OFF_W116  (353231872ll)
#define OFF_WQ16  (353305600ll)
#define OFF_W3P   (353526784ll)
#define OFF_MCOMB (354190336ll)
#define OFF_WDWT  (354780160ll)

__device__ __forceinline__ void async16(const void* g, void* l) {
  __builtin_amdgcn_global_load_lds(
      (const __attribute__((address_space(1))) unsigned int*)g,
      (__attribute__((address_space(3))) unsigned int*)l, 16, 0, 0);
}
#define MFMA(a,b,c) __builtin_amdgcn_mfma_f32_16x16x32_f16((a),(b),(c),0,0,0)

// ---------------------------------------------------------------------------
// P2: cast/pack all weights to f16. w3 repacked [tap][co][ci]; wdw repacked+cast
// to wdwT[tap][gc] (f16) so k_dw can load 8 channels' weights as one 16B read.
__global__ void k_wcast(const float* __restrict__ w1, const float* __restrict__ wq,
                        const float* __restrict__ w3, const float* __restrict__ wdw,
                        f16* __restrict__ w1o, f16* __restrict__ wqo,
                        f16* __restrict__ w3p, f16* __restrict__ wdwT)
{
  int idx = blockIdx.x * 256 + threadIdx.x;              // 484416 total
  if (idx < 36864) {
    w1o[idx] = (f16)w1[idx];
  } else if (idx < 147456) {
    int i = idx - 36864;
    wqo[i] = (f16)wq[i];
  } else if (idx < 479232) {
    int i = idx - 147456;
    int tap = i / 36864;
    int rem = i % 36864;                                 // co*192+ci
    w3p[i] = (f16)w3[(size_t)rem * 9 + tap];
  } else if (idx < 484416) {
    int i = idx - 479232;                                // 5184 = 9*576
    int tap = i / 576;
    int gc = i % 576;
    wdwT[i] = (f16)wdw[(size_t)gc * 9 + tap];
  }
}

// ---------------------------------------------------------------------------
// P1: transpose-cast x,cn : fp32 [b][c][s] -> f16 [b][s][c]
__global__ __launch_bounds__(256)
void k_cast_t(const float* __restrict__ xin, const float* __restrict__ cnin,
              f16* __restrict__ xo, f16* __restrict__ cno)
{
  __shared__ f16 tile[64 * 66];
  int b = blockIdx.z & 7;
  const float* in = (blockIdx.z >= 8) ? cnin : xin;
  f16* out = (blockIdx.z >= 8) ? cno : xo;
  int s0 = blockIdx.x * 64, c0 = blockIdx.y * 64;
  int t = threadIdx.x;
  int sl = t & 63, cq = t >> 6;
#pragma unroll
  for (int r = 0; r < 16; ++r) {
    int cl = r * 4 + cq;
    float v = in[((size_t)b * NC + c0 + cl) * NS + s0 + sl];
    tile[cl * 66 + sl] = (f16)v;
  }
  __syncthreads();
  int cl2 = t & 63, sq = t >> 6;
#pragma unroll
  for (int r = 0; r < 16; ++r) {
    int sl2 = r * 4 + sq;
    out[((size_t)b * NS + s0 + sl2) * NC + c0 + cl2] = tile[cl2 * 66 + sl2];
  }
}

// ---------------------------------------------------------------------------
// BT-GEMM: out[b][s][co] = sum_ci act[b][s][ci] * wt[co][ci]. M=s tile 256, N=co 64, K=192.
__global__ __launch_bounds__(256, 2)
void k_gemm_act(const f16* __restrict__ act, const f16* __restrict__ wt,
                f16* __restrict__ out)
{
  __shared__ f16 At[256 * 32];
  __shared__ f16 Bt[64 * 32];
  const int tid = threadIdx.x;
  const int b = blockIdx.z;
  const int s0 = blockIdx.x * 256;
  const int n0 = blockIdx.y * 64;
  const int w = tid >> 6, lane = tid & 63, quad = lane >> 4, l16 = lane & 15;
  const f16* actB = act + (size_t)b * NS * NC;

  const f32x4 Z = {0.f, 0.f, 0.f, 0.f};
  f32x4 acc[4][4];
#pragma unroll
  for (int i = 0; i < 4; ++i)
#pragma unroll
    for (int j = 0; j < 4; ++j) acc[i][j] = Z;

  for (int kc = 0; kc < 6; ++kc) {
    const int k0 = kc * 32;
#pragma unroll
    for (int i = 0; i < 4; ++i) {
      int r = i * 64 + (w << 4) + (lane >> 2);
      int col = k0 + ((((lane & 3) + (r >> 2)) & 3) << 3);
      async16(actB + (size_t)(s0 + r) * NC + col, At + (size_t)(i * 64 + (w << 4)) * 32);
    }
    {
      int rb = (w << 4) + (lane >> 2);
      int colb = k0 + ((((lane & 3) + (rb >> 2)) & 3) << 3);
      async16(wt + (size_t)(n0 + rb) * NC + colb, Bt + (size_t)(w << 4) * 32);
    }
    __syncthreads();

    f16x8 bf[4];
#pragma unroll
    for (int nt = 0; nt < 4; ++nt) {
      int n = nt * 16 + l16;
      int p = (quad - (n >> 2)) & 3;
      bf[nt] = *(const f16x8*)(Bt + n * 32 + p * 8);
    }
#pragma unroll
    for (int mt = 0; mt < 4; ++mt) {
      int m = w * 64 + mt * 16 + l16;
      int p = (quad - (m >> 2)) & 3;
      f16x8 af = *(const f16x8*)(At + m * 32 + p * 8);
#pragma unroll
      for (int nt = 0; nt < 4; ++nt) acc[mt][nt] = MFMA(af, bf[nt], acc[mt][nt]);
    }
    __syncthreads();
  }
#pragma unroll
  for (int mt = 0; mt < 4; ++mt)
#pragma unroll
    for (int r = 0; r < 4; ++r) {
      int sg = s0 + w * 64 + mt * 16 + quad * 4 + r;
      f16* o = out + ((size_t)b * NS + sg) * NC + n0;
#pragma unroll
      for (int nt = 0; nt < 4; ++nt) o[nt * 16 + l16] = (f16)acc[mt][nt][r];
    }
}

// ---------------------------------------------------------------------------
// conv3x3 implicit GEMM: out[b][s][co] = sum_tap sum_ci act[b][s+off][ci]*w3p[tap][co][ci]
__global__ __launch_bounds__(256, 2)
void k_conv3(const f16* __restrict__ act, const f16* __restrict__ w3p,
             f16* __restrict__ out, const f16* __restrict__ zpad)
{
  __shared__ f16 At[256 * 32];
  __shared__ f16 Bt[64 * 32];
  const int tid = threadIdx.x;
  const int b = blockIdx.z;
  const int s0 = blockIdx.x * 256;
  const int n0 = blockIdx.y * 64;
  const int w = tid >> 6, lane = tid & 63, quad = lane >> 4, l16 = lane & 15;
  const f16* actB = act + (size_t)b * NS * NC;

  const f32x4 Z = {0.f, 0.f, 0.f, 0.f};
  f32x4 acc[4][4];
#pragma unroll
  for (int i = 0; i < 4; ++i)
#pragma unroll
    for (int j = 0; j < 4; ++j) acc[i][j] = Z;

  for (int tap = 0; tap < 9; ++tap) {
    const int dy = tap / 3 - 1, dx = tap % 3 - 1;
    const int off = dy * 128 + dx;
    const f16* wt = w3p + (size_t)tap * NC * NC;
    for (int kc = 0; kc < 6; ++kc) {
      const int k0 = kc * 32;
#pragma unroll
      for (int i = 0; i < 4; ++i) {
        int r = i * 64 + (w << 4) + (lane >> 2);
        int sg = s0 + r;
        int x = sg & 127, y = sg >> 7;
        bool valid = ((unsigned)(x + dx) < 128u) && ((unsigned)(y + dy) < 128u);
        int col = k0 + ((((lane & 3) + (r >> 2)) & 3) << 3);
        const f16* g = valid ? (actB + (size_t)(sg + off) * NC + col) : zpad;
        async16(g, At + (size_t)(i * 64 + (w << 4)) * 32);
      }
      {
        int rb = (w << 4) + (lane >> 2);
        int colb = k0 + ((((lane & 3) + (rb >> 2)) & 3) << 3);
        async16(wt + (size_t)(n0 + rb) * NC + colb, Bt + (size_t)(w << 4) * 32);
      }
      __syncthreads();
      f16x8 bf[4];
#pragma unroll
      for (int nt = 0; nt < 4; ++nt) {
        int n = nt * 16 + l16;
        int p = (quad - (n >> 2)) & 3;
        bf[nt] = *(const f16x8*)(Bt + n * 32 + p * 8);
      }
#pragma unroll
      for (int mt = 0; mt < 4; ++mt) {
        int m = w * 64 + mt * 16 + l16;
        int p = (quad - (m >> 2)) & 3;
        f16x8 af = *(const f16x8*)(At + m * 32 + p * 8);
#pragma unroll
        for (int nt = 0; nt < 4; ++nt) acc[mt][nt] = MFMA(af, bf[nt], acc[mt][nt]);
      }
      __syncthreads();
    }
  }
#pragma unroll
  for (int mt = 0; mt < 4; ++mt)
#pragma unroll
    for (int r = 0; r < 4; ++r) {
      int sg = s0 + w * 64 + mt * 16 + quad * 4 + r;
      f16* o = out + ((size_t)b * NS + sg) * NC + n0;
#pragma unroll
      for (int nt = 0; nt < 4; ++nt) o[nt * 16 + l16] = (f16)acc[mt][nt][r];
    }
}

// ---------------------------------------------------------------------------
// depthwise 3x3, 8-channel vectorized: one thread = 8 consecutive channels of one s.
// in [b][s][192] f16 -> out [b][s][576] (cols part*192..+191). Weights wdwT[tap][gc] f16.
__global__ __launch_bounds__(256)
void k_dw(const f16* __restrict__ in, const f16* __restrict__ wdwT,
          f16* __restrict__ out, int part)
{
  int idx = blockIdx.x * 256 + threadIdx.x;   // exact 3145728 = 8*16384*24
  int cg = idx % 24;
  int s = (idx / 24) % NS;
  int b = idx / (24 * NS);
  int x = s & 127, y = s >> 7;
  const f16* ip = in + ((size_t)b * NS + s) * NC + cg * 8;
  const f16* wp = wdwT + part * NC + cg * 8;
  float a[8] = {0.f, 0.f, 0.f, 0.f, 0.f, 0.f, 0.f, 0.f};
#pragma unroll
  for (int t = 0; t < 9; ++t) {
    int dy = t / 3 - 1, dx = t % 3 - 1;
    if (((unsigned)(x + dx) < 128u) && ((unsigned)(y + dy) < 128u)) {
      f16x8 v = *(const f16x8*)(ip + (dy * 128 + dx) * NC);
      f16x8 wv = *(const f16x8*)(wp + t * NC3);
#pragma unroll
      for (int j = 0; j < 8; ++j) a[j] += (float)wv[j] * (float)v[j];
    }
  }
  f16x8 o;
#pragma unroll
  for (int j = 0; j < 8; ++j) o[j] = (f16)a[j];
  *(f16x8*)(out + ((size_t)b * NS + s) * NC3 + part * NC + cg * 8) = o;
}

// ---------------------------------------------------------------------------
// E1: per (b,c): sum q^2, k^2, cn^2, q*cn over spatial. 8-channel vectorized:
// block 192 = 24 channel-groups x 8 s-rows; each thread accumulates 8ch x 4 stats.
__global__ __launch_bounds__(192)
void k_e1(const f16* __restrict__ qkvd, const f16* __restrict__ cnf,
          float* __restrict__ norms)
{
  int blk = blockIdx.x;                 // b(8) x chunk(64)
  int b = blk >> 6;
  int chunk = blk & 63;
  int tid = threadIdx.x;
  int cg = tid % 24;
  int srow = tid / 24;                  // 0..7
  float q2[8], k2[8], cn2[8], qc[8];
#pragma unroll
  for (int j = 0; j < 8; ++j) { q2[j] = 0.f; k2[j] = 0.f; cn2[j] = 0.f; qc[j] = 0.f; }
  int sBase = chunk * 256;
  for (int s8 = srow; s8 < 256; s8 += 8) {
    size_t row = (size_t)b * NS + sBase + s8;
    f16x8 q = *(const f16x8*)(qkvd + row * NC3 + cg * 8);
    f16x8 k = *(const f16x8*)(qkvd + row * NC3 + 192 + cg * 8);
    f16x8 n = *(const f16x8*)(cnf + row * NC + cg * 8);
#pragma unroll
    for (int j = 0; j < 8; ++j) {
      float qf = (float)q[j], kf = (float)k[j], nf = (float)n[j];
      q2[j] += qf * qf; k2[j] += kf * kf; cn2[j] += nf * nf; qc[j] += qf * nf;
    }
  }
#pragma unroll
  for (int j = 0; j < 8; ++j) {
    float* np = norms + ((size_t)b * NC + cg * 8 + j) * 4;
    atomicAdd(np + 0, q2[j]); atomicAdd(np + 1, k2[j]);
    atomicAdd(np + 2, cn2[j]); atomicAdd(np + 3, qc[j]);
  }
}

// ---------------------------------------------------------------------------
// E2: G1[b,h,c,d]=sum_s q*k ; G2=sum_s cn*k. 1 wave/block, LDS transpose staging + MFMA.
__global__ __launch_bounds__(64)
void k_e2(const f16* __restrict__ qkvd, const f16* __restrict__ cnf,
          float* __restrict__ G1, float* __restrict__ G2)
{
  __shared__ f16 qT[48 * 72];
  __shared__ f16 kT[48 * 72];
  __shared__ f16 cT[48 * 72];
  int blk = blockIdx.x;               // b(8) x h(4) x split(16)
  int split = blk & 15;
  int h = (blk >> 4) & 3;
  int b = blk >> 6;
  int lane = threadIdx.x, quad = lane >> 4, l16 = lane & 15;
  const f32x4 Z = {0.f, 0.f, 0.f, 0.f};
  f32x4 g1[3][3], g2[3][3];
#pragma unroll
  for (int i = 0; i < 3; ++i)
#pragma unroll
    for (int j = 0; j < 3; ++j) { g1[i][j] = Z; g2[i][j] = Z; }

  int sBase = split * 1024;
  for (int chunk = 0; chunk < 16; ++chunk) {
    int sb = sBase + chunk * 64;
    __syncthreads();
#pragma unroll
    for (int it = 0; it < 24; ++it) {
      int idx = it * 64 + lane;       // 1536 = 64 rows x 24 u32
      int r = idx / 24;
      int cw = idx % 24;
      const f16* qrow = qkvd + ((size_t)b * NS + sb + r) * NC3 + h * 48;
      const f16* crow = cnf + ((size_t)b * NS + sb + r) * NC + h * 48;
      unsigned qv = *(const unsigned*)(qrow + cw * 2);
      unsigned kv = *(const unsigned*)(qrow + 192 + cw * 2);
      unsigned nv = *(const unsigned*)(crow + cw * 2);
      qT[(cw * 2) * 72 + r] = ((const f16*)&qv)[0];
      qT[(cw * 2 + 1) * 72 + r] = ((const f16*)&qv)[1];
      kT[(cw * 2) * 72 + r] = ((const f16*)&kv)[0];
      kT[(cw * 2 + 1) * 72 + r] = ((const f16*)&kv)[1];
      cT[(cw * 2) * 72 + r] = ((const f16*)&nv)[0];
      cT[(cw * 2 + 1) * 72 + r] = ((const f16*)&nv)[1];
    }
    __syncthreads();
#pragma unroll
    for (int kk = 0; kk < 2; ++kk) {
      int ko = kk * 32 + quad * 8;
      f16x8 bfr[3];
#pragma unroll
      for (int dt = 0; dt < 3; ++dt) bfr[dt] = *(const f16x8*)(kT + (dt * 16 + l16) * 72 + ko);
#pragma unroll
      for (int ct = 0; ct < 3; ++ct) {
        f16x8 aq = *(const f16x8*)(qT + (ct * 16 + l16) * 72 + ko);
        f16x8 an = *(const f16x8*)(cT + (ct * 16 + l16) * 72 + ko);
#pragma unroll
        for (int dt = 0; dt < 3; ++dt) {
          g1[ct][dt] = MFMA(aq, bfr[dt], g1[ct][dt]);
          g2[ct][dt] = MFMA(an, bfr[dt], g2[ct][dt]);
        }
      }
    }
  }
#pragma unroll
  for (int ct = 0; ct < 3; ++ct)
#pragma unroll
    for (int dt = 0; dt < 3; ++dt)
#pragma unroll
      for (int r = 0; r < 4; ++r) {
        int c = ct * 16 + quad * 4 + r;
        int d = dt * 16 + l16;
        size_t o = (((size_t)(b * NHD + h) * 48 + c) * 48 + d);
        atomicAdd(G1 + o, g1[ct][dt][r]);
        atomicAdd(G2 + o, g2[ct][dt][r]);
      }
}

// ---------------------------------------------------------------------------
// F1: logits + softmax -> attn[b][h][c][d] (fp32)
__global__ __launch_bounds__(64)
void k_f1(const float* __restrict__ G1, const float* __restrict__ G2,
          const float* __restrict__ norms, const float* __restrict__ temp,
          float* __restrict__ attn)
{
  __shared__ float S[48 * 48];
  int h = blockIdx.x & 3, b = blockIdx.x >> 2;
  int t = threadIdx.x;
  float T = temp[h];
  const float EPS = 1e-12f;
#pragma unroll
  for (int i = 0; i < 36; ++i) {
    int idx = i * 64 + t;
    int c = idx / 48, d = idx % 48;
    const float* np = norms + ((size_t)b * NC + h * 48 + c) * 4;
    float q2 = np[0], cn2 = np[2], qc = np[3];
    float nq = fmaxf(sqrtf(q2), EPS);
    float ncn = fmaxf(sqrtf(cn2), EPS);
    float k2 = norms[((size_t)b * NC + h * 48 + d) * 4 + 1];
    float nk = fmaxf(sqrtf(k2), EPS);
    float ss = q2 / (nq * nq) + 2.f * qc / (nq * ncn) + cn2 / (ncn * ncn);
    float nsum = fmaxf(sqrtf(fmaxf(ss, 0.f)), EPS);
    size_t go = (((size_t)(b * NHD + h) * 48 + c) * 48 + d);
    S[idx] = (G1[go] / nq + G2[go] / ncn) / (nsum * nk) * T;
  }
  __syncthreads();
  if (t < 48) {
    float mx = -1e30f;
    for (int d = 0; d < 48; ++d) mx = fmaxf(mx, S[t * 48 + d]);
    float sum = 0.f;
    for (int d = 0; d < 48; ++d) { float e = expf(S[t * 48 + d] - mx); S[t * 48 + d] = e; sum += e; }
    float inv = 1.f / sum;
    float* ap = attn + (((size_t)(b * NHD + h) * 48 + t) * 48);
    for (int d = 0; d < 48; ++d) ap[d] = S[t * 48 + d] * inv;
  }
}

// ---------------------------------------------------------------------------
// F2: Mcomb[b][co][dg] = sum_cl projw[co][h*48+cl] * attn[b][h][cl][dg%48]  (f16 out)
__global__ void k_f2(const float* __restrict__ attn, const float* __restrict__ projw,
                     f16* __restrict__ mcomb)
{
  int idx = blockIdx.x * 256 + threadIdx.x;   // 294912 exact
  int dg = idx % NC;
  int co = (idx / NC) % NC;
  int b = idx / (NC * NC);
  int h = dg / 48, dl = dg % 48;
  const float* pw = projw + (size_t)co * NC + h * 48;
  const float* at = attn + ((size_t)(b * NHD + h) * 48) * 48 + dl;
  float a = 0.f;
#pragma unroll
  for (int cl = 0; cl < 48; ++cl) a += pw[cl] * at[cl * 48];
  mcomb[idx] = (f16)a;
}

// ---------------------------------------------------------------------------
// G: out[b][co][s] = sum_dg mcomb[b][co][dg] * v[b][s][dg]  (v = qkvd cols 384..575), fp32 out
__global__ __launch_bounds__(256, 2)
void k_gemm_out(const f16* __restrict__ mcomb, const f16* __restrict__ qkvd,
                float* __restrict__ out)
{
  __shared__ f16 At[64 * 32];
  __shared__ f16 Bt[256 * 32];
  const int tid = threadIdx.x;
  const int b = blockIdx.z;
  const int s0 = blockIdx.x * 256;
  const int m0 = blockIdx.y * 64;
  const int w = tid >> 6, lane = tid & 63, quad = lane >> 4, l16 = lane & 15;
  const f16* mcB = mcomb + (size_t)b * NC * NC;
  const f16* vB = qkvd + (size_t)b * NS * NC3 + 384;

  const f32x4 Z = {0.f, 0.f, 0.f, 0.f};
  f32x4 acc[4][4];
#pragma unroll
  for (int i = 0; i < 4; ++i)
#pragma unroll
    for (int j = 0; j < 4; ++j) acc[i][j] = Z;

  for (int kc = 0; kc < 6; ++kc) {
    const int k0 = kc * 32;
    {
      int rb = (w << 4) + (lane >> 2);
      int colb = k0 + ((((lane & 3) + (rb >> 2)) & 3) << 3);
      async16(mcB + (size_t)(m0 + rb) * NC + colb, At + (size_t)(w << 4) * 32);
    }
#pragma unroll
    for (int i = 0; i < 4; ++i) {
      int r = i * 64 + (w << 4) + (lane >> 2);
      int col = k0 + ((((lane & 3) + (r >> 2)) & 3) << 3);
      async16(vB + (size_t)(s0 + r) * NC3 + col, Bt + (size_t)(i * 64 + (w << 4)) * 32);
    }
    __syncthreads();
    f16x8 af[4];
#pragma unroll
    for (int mt = 0; mt < 4; ++mt) {
      int m = mt * 16 + l16;
      int p = (quad - (m >> 2)) & 3;
      af[mt] = *(const f16x8*)(At + m * 32 + p * 8);
    }
#pragma unroll
    for (int nt = 0; nt < 4; ++nt) {
      int n = w * 64 + nt * 16 + l16;
      int p = (quad - (n >> 2)) & 3;
      f16x8 bf = *(const f16x8*)(Bt + n * 32 + p * 8);
#pragma unroll
      for (int mt = 0; mt < 4; ++mt) acc[mt][nt] = MFMA(af[mt], bf, acc[mt][nt]);
    }
    __syncthreads();
  }
#pragma unroll
  for (int mt = 0; mt < 4; ++mt)
#pragma unroll
    for (int r = 0; r < 4; ++r) {
      int cog = m0 + mt * 16 + quad * 4 + r;
      float* o = out + ((size_t)b * NC + cog) * NS + s0 + w * 64;
#pragma unroll
      for (int nt = 0; nt < 4; ++nt) o[nt * 16 + l16] = acc[mt][nt][r];
    }
}

// ---------------------------------------------------------------------------
extern "C" void kernel_launch(void* const* d_in, const int* in_sizes, int n_in,
                              void* d_out, int out_size, void* d_ws, size_t ws_size,
                              hipStream_t stream) {
  const float* x   = (const float*)d_in[0];
  const float* cn  = (const float*)d_in[1];
  const float* w1  = (const float*)d_in[2];
  const float* w3  = (const float*)d_in[3];
  const float* wq  = (const float*)d_in[4];
  const float* wdw = (const float*)d_in[5];
  const float* wpj = (const float*)d_in[6];
  const float* tmp = (const float*)d_in[7];
  float* out = (float*)d_out;
  char* ws = (char*)d_ws;

  f16* x16    = (f16*)(ws + OFF_X16);
  f16* cn16   = (f16*)(ws + OFF_CN16);
  f16* qkv1p  = (f16*)(ws + OFF_CN16);   // overlay: cn16 dead after kernel A
  f16* cn1    = (f16*)(ws + OFF_CN1);
  f16* cnf    = (f16*)(ws + OFF_CNF);
  f16* qkvd   = (f16*)(ws + OFF_QKVD);
  float* norms = (float*)(ws + OFF_NORMS);
  float* G1    = (float*)(ws + OFF_G1);
  float* G2    = (float*)(ws + OFF_G2);
  f16* zpad   = (f16*)(ws + OFF_ZPAD);
  float* attn  = (float*)(ws + OFF_ATTN);
  f16* w116   = (f16*)(ws + OFF_W116);
  f16* wq16   = (f16*)(ws + OFF_WQ16);
  f16* w3p    = (f16*)(ws + OFF_W3P);
  f16* mcomb  = (f16*)(ws + OFF_MCOMB);
  f16* wdwT   = (f16*)(ws + OFF_WDWT);

  // zero accumulators (norms, G1, G2) + zero page
  hipMemsetAsync(ws + OFF_NORMS, 0, 615424, stream);

  k_wcast<<<1893, 256, 0, stream>>>(w1, wq, w3, wdw, w116, wq16, w3p, wdwT);
  k_cast_t<<<dim3(256, 3, 16), 256, 0, stream>>>(x, cn, x16, cn16);
  k_gemm_act<<<dim3(64, 3, 8), 256, 0, stream>>>(cn16, w116, cn1);
  k_conv3<<<dim3(64, 3, 8), 256, 0, stream>>>(cn1, w3p, cnf, zpad);
  for (int p = 0; p < 3; ++p) {
    k_gemm_act<<<dim3(64, 3, 8), 256, 0, stream>>>(x16, wq16 + p * 36864, qkv1p);
    k_dw<<<12288, 256, 0, stream>>>(qkv1p, wdwT, qkvd, p);
  }
  k_e1<<<512, 192, 0, stream>>>(qkvd, cnf, norms);
  k_e2<<<512, 64, 0, stream>>>(qkvd, cnf, G1, G2);
  k_f1<<<32, 64, 0, stream>>>(G1, G2, norms, tmp, attn);
  k_f2<<<1152, 256, 0, stream>>>(attn, wpj, mcomb);
  k_gemm_out<<<dim3(64, 3, 8), 256, 0, stream>>>(mcomb, qkvd, out);

  (void)in_sizes; (void)n_in; (void)out_size; (void)ws_size;
}

// Round 3
// 749.362 us; speedup vs baseline: 1.6966x; 1.4143x over previous
//
#include <hip/hip_runtime.h>
#include <hip/hip_bf16.h>

typedef _Float16 f16;
typedef _Float16 f16x8 __attribute__((ext_vector_type(8)));
typedef float f32x4 __attribute__((ext_vector_type(4)));

#define NB 8
#define NC 192
#define NC3 576
#define NS 16384
#define NHD 4

// ---- workspace offsets (bytes). total ~355 MB ----
#define OFF_X16   (0ll)
#define OFF_CN16  (50331648ll)     // reused as qkv1 part buffer after kernel A
#define OFF_CN1   (100663296ll)
#define OFF_CNF   (150994944ll)
#define OFF_QKVD  (201326592ll)
#define OFF_NORMS (352321536ll)
#define OFF_G1    (352346112ll)
#define OFF_G2    (352641024ll)
#define OFF_ZPAD  (352935936ll)
#define OFF_ATTN  (352936960ll)
#define OFF_W116  (353231872ll)
#define OFF_WQ16  (353305600ll)
#define OFF_W3P   (353526784ll)
#define OFF_MCOMB (354190336ll)
#define OFF_WDWT  (354780160ll)
// E-stage partials overlay the dead cn1 buffer [OFF_CN1, OFF_CN1+50MB)
#define OFF_G1P   (100663296ll)               // 8*4*32*2304*4 = 9437184
#define OFF_G2P   (110100480ll)               // 9437184
#define OFF_NPART (119537664ll)               // 8*32*192*4*4 = 786432

__device__ __forceinline__ void async16(const void* g, void* l) {
  __builtin_amdgcn_global_load_lds(
      (const __attribute__((address_space(1))) unsigned int*)g,
      (__attribute__((address_space(3))) unsigned int*)l, 16, 0, 0);
}
#define MFMA(a,b,c) __builtin_amdgcn_mfma_f32_16x16x32_f16((a),(b),(c),0,0,0)

// ---------------------------------------------------------------------------
// P2: cast/pack all weights to f16. w3 repacked [tap][co][ci]; wdw repacked+cast
// to wdwT[tap][gc] (f16) so k_dw can load 8 channels' weights as one 16B read.
__global__ void k_wcast(const float* __restrict__ w1, const float* __restrict__ wq,
                        const float* __restrict__ w3, const float* __restrict__ wdw,
                        f16* __restrict__ w1o, f16* __restrict__ wqo,
                        f16* __restrict__ w3p, f16* __restrict__ wdwT)
{
  int idx = blockIdx.x * 256 + threadIdx.x;              // 484416 total
  if (idx < 36864) {
    w1o[idx] = (f16)w1[idx];
  } else if (idx < 147456) {
    int i = idx - 36864;
    wqo[i] = (f16)wq[i];
  } else if (idx < 479232) {
    int i = idx - 147456;
    int tap = i / 36864;
    int rem = i % 36864;                                 // co*192+ci
    w3p[i] = (f16)w3[(size_t)rem * 9 + tap];
  } else if (idx < 484416) {
    int i = idx - 479232;                                // 5184 = 9*576
    int tap = i / 576;
    int gc = i % 576;
    wdwT[i] = (f16)wdw[(size_t)gc * 9 + tap];
  }
}

// ---------------------------------------------------------------------------
// P1: transpose-cast x,cn : fp32 [b][c][s] -> f16 [b][s][c]
__global__ __launch_bounds__(256)
void k_cast_t(const float* __restrict__ xin, const float* __restrict__ cnin,
              f16* __restrict__ xo, f16* __restrict__ cno)
{
  __shared__ f16 tile[64 * 66];
  int b = blockIdx.z & 7;
  const float* in = (blockIdx.z >= 8) ? cnin : xin;
  f16* out = (blockIdx.z >= 8) ? cno : xo;
  int s0 = blockIdx.x * 64, c0 = blockIdx.y * 64;
  int t = threadIdx.x;
  int sl = t & 63, cq = t >> 6;
#pragma unroll
  for (int r = 0; r < 16; ++r) {
    int cl = r * 4 + cq;
    float v = in[((size_t)b * NC + c0 + cl) * NS + s0 + sl];
    tile[cl * 66 + sl] = (f16)v;
  }
  __syncthreads();
  int cl2 = t & 63, sq = t >> 6;
#pragma unroll
  for (int r = 0; r < 16; ++r) {
    int sl2 = r * 4 + sq;
    out[((size_t)b * NS + s0 + sl2) * NC + c0 + cl2] = tile[cl2 * 66 + sl2];
  }
}

// ---------------------------------------------------------------------------
// BT-GEMM: out[b][s][co] = sum_ci act[b][s][ci] * wt[co][ci]. M=s tile 256, N=co 64, K=192.
__global__ __launch_bounds__(256, 2)
void k_gemm_act(const f16* __restrict__ act, const f16* __restrict__ wt,
                f16* __restrict__ out)
{
  __shared__ f16 At[256 * 32];
  __shared__ f16 Bt[64 * 32];
  const int tid = threadIdx.x;
  const int b = blockIdx.z;
  const int s0 = blockIdx.x * 256;
  const int n0 = blockIdx.y * 64;
  const int w = tid >> 6, lane = tid & 63, quad = lane >> 4, l16 = lane & 15;
  const f16* actB = act + (size_t)b * NS * NC;

  const f32x4 Z = {0.f, 0.f, 0.f, 0.f};
  f32x4 acc[4][4];
#pragma unroll
  for (int i = 0; i < 4; ++i)
#pragma unroll
    for (int j = 0; j < 4; ++j) acc[i][j] = Z;

  for (int kc = 0; kc < 6; ++kc) {
    const int k0 = kc * 32;
#pragma unroll
    for (int i = 0; i < 4; ++i) {
      int r = i * 64 + (w << 4) + (lane >> 2);
      int col = k0 + ((((lane & 3) + (r >> 2)) & 3) << 3);
      async16(actB + (size_t)(s0 + r) * NC + col, At + (size_t)(i * 64 + (w << 4)) * 32);
    }
    {
      int rb = (w << 4) + (lane >> 2);
      int colb = k0 + ((((lane & 3) + (rb >> 2)) & 3) << 3);
      async16(wt + (size_t)(n0 + rb) * NC + colb, Bt + (size_t)(w << 4) * 32);
    }
    __syncthreads();

    f16x8 bf[4];
#pragma unroll
    for (int nt = 0; nt < 4; ++nt) {
      int n = nt * 16 + l16;
      int p = (quad - (n >> 2)) & 3;
      bf[nt] = *(const f16x8*)(Bt + n * 32 + p * 8);
    }
#pragma unroll
    for (int mt = 0; mt < 4; ++mt) {
      int m = w * 64 + mt * 16 + l16;
      int p = (quad - (m >> 2)) & 3;
      f16x8 af = *(const f16x8*)(At + m * 32 + p * 8);
#pragma unroll
      for (int nt = 0; nt < 4; ++nt) acc[mt][nt] = MFMA(af, bf[nt], acc[mt][nt]);
    }
    __syncthreads();
  }
#pragma unroll
  for (int mt = 0; mt < 4; ++mt)
#pragma unroll
    for (int r = 0; r < 4; ++r) {
      int sg = s0 + w * 64 + mt * 16 + quad * 4 + r;
      f16* o = out + ((size_t)b * NS + sg) * NC + n0;
#pragma unroll
      for (int nt = 0; nt < 4; ++nt) o[nt * 16 + l16] = (f16)acc[mt][nt][r];
    }
}

// ---------------------------------------------------------------------------
// conv3x3 implicit GEMM: out[b][s][co] = sum_tap sum_ci act[b][s+off][ci]*w3p[tap][co][ci]
__global__ __launch_bounds__(256, 2)
void k_conv3(const f16* __restrict__ act, const f16* __restrict__ w3p,
             f16* __restrict__ out, const f16* __restrict__ zpad)
{
  __shared__ f16 At[256 * 32];
  __shared__ f16 Bt[64 * 32];
  const int tid = threadIdx.x;
  const int b = blockIdx.z;
  const int s0 = blockIdx.x * 256;
  const int n0 = blockIdx.y * 64;
  const int w = tid >> 6, lane = tid & 63, quad = lane >> 4, l16 = lane & 15;
  const f16* actB = act + (size_t)b * NS * NC;

  const f32x4 Z = {0.f, 0.f, 0.f, 0.f};
  f32x4 acc[4][4];
#pragma unroll
  for (int i = 0; i < 4; ++i)
#pragma unroll
    for (int j = 0; j < 4; ++j) acc[i][j] = Z;

  for (int tap = 0; tap < 9; ++tap) {
    const int dy = tap / 3 - 1, dx = tap % 3 - 1;
    const int off = dy * 128 + dx;
    const f16* wt = w3p + (size_t)tap * NC * NC;
    for (int kc = 0; kc < 6; ++kc) {
      const int k0 = kc * 32;
#pragma unroll
      for (int i = 0; i < 4; ++i) {
        int r = i * 64 + (w << 4) + (lane >> 2);
        int sg = s0 + r;
        int x = sg & 127, y = sg >> 7;
        bool valid = ((unsigned)(x + dx) < 128u) && ((unsigned)(y + dy) < 128u);
        int col = k0 + ((((lane & 3) + (r >> 2)) & 3) << 3);
        const f16* g = valid ? (actB + (size_t)(sg + off) * NC + col) : zpad;
        async16(g, At + (size_t)(i * 64 + (w << 4)) * 32);
      }
      {
        int rb = (w << 4) + (lane >> 2);
        int colb = k0 + ((((lane & 3) + (rb >> 2)) & 3) << 3);
        async16(wt + (size_t)(n0 + rb) * NC + colb, Bt + (size_t)(w << 4) * 32);
      }
      __syncthreads();
      f16x8 bf[4];
#pragma unroll
      for (int nt = 0; nt < 4; ++nt) {
        int n = nt * 16 + l16;
        int p = (quad - (n >> 2)) & 3;
        bf[nt] = *(const f16x8*)(Bt + n * 32 + p * 8);
      }
#pragma unroll
      for (int mt = 0; mt < 4; ++mt) {
        int m = w * 64 + mt * 16 + l16;
        int p = (quad - (m >> 2)) & 3;
        f16x8 af = *(const f16x8*)(At + m * 32 + p * 8);
#pragma unroll
        for (int nt = 0; nt < 4; ++nt) acc[mt][nt] = MFMA(af, bf[nt], acc[mt][nt]);
      }
      __syncthreads();
    }
  }
#pragma unroll
  for (int mt = 0; mt < 4; ++mt)
#pragma unroll
    for (int r = 0; r < 4; ++r) {
      int sg = s0 + w * 64 + mt * 16 + quad * 4 + r;
      f16* o = out + ((size_t)b * NS + sg) * NC + n0;
#pragma unroll
      for (int nt = 0; nt < 4; ++nt) o[nt * 16 + l16] = (f16)acc[mt][nt][r];
    }
}

// ---------------------------------------------------------------------------
// depthwise 3x3, 8-channel vectorized: one thread = 8 consecutive channels of one s.
__global__ __launch_bounds__(256)
void k_dw(const f16* __restrict__ in, const f16* __restrict__ wdwT,
          f16* __restrict__ out, int part)
{
  int idx = blockIdx.x * 256 + threadIdx.x;   // exact 3145728 = 8*16384*24
  int cg = idx % 24;
  int s = (idx / 24) % NS;
  int b = idx / (24 * NS);
  int x = s & 127, y = s >> 7;
  const f16* ip = in + ((size_t)b * NS + s) * NC + cg * 8;
  const f16* wp = wdwT + part * NC + cg * 8;
  float a[8] = {0.f, 0.f, 0.f, 0.f, 0.f, 0.f, 0.f, 0.f};
#pragma unroll
  for (int t = 0; t < 9; ++t) {
    int dy = t / 3 - 1, dx = t % 3 - 1;
    if (((unsigned)(x + dx) < 128u) && ((unsigned)(y + dy) < 128u)) {
      f16x8 v = *(const f16x8*)(ip + (dy * 128 + dx) * NC);
      f16x8 wv = *(const f16x8*)(wp + t * NC3);
#pragma unroll
      for (int j = 0; j < 8; ++j) a[j] += (float)wv[j] * (float)v[j];
    }
  }
  f16x8 o;
#pragma unroll
  for (int j = 0; j < 8; ++j) o[j] = (f16)a[j];
  *(f16x8*)(out + ((size_t)b * NS + s) * NC3 + part * NC + cg * 8) = o;
}

// ---------------------------------------------------------------------------
// E2 (fused with E1): per (b,h,split of 512 s): G1p = Q*K^T, G2p = CN*K^T partials
// via LDS-transpose + MFMA; per-channel stats (q2,k2,cn2,qc) from the same
// fragments, shfl-reduced across quads. NO ATOMICS.
__global__ __launch_bounds__(64)
void k_e2(const f16* __restrict__ qkvd, const f16* __restrict__ cnf,
          float* __restrict__ G1p, float* __restrict__ G2p,
          float* __restrict__ npart)
{
  __shared__ f16 qT[48 * 72];
  __shared__ f16 kT[48 * 72];
  __shared__ f16 cT[48 * 72];
  int blk = blockIdx.x;               // b(8) x h(4) x split(32)
  int split = blk & 31;
  int h = (blk >> 5) & 3;
  int b = blk >> 7;
  int lane = threadIdx.x, quad = lane >> 4, l16 = lane & 15;
  const f32x4 Z = {0.f, 0.f, 0.f, 0.f};
  f32x4 g1[3][3], g2[3][3];
#pragma unroll
  for (int i = 0; i < 3; ++i)
#pragma unroll
    for (int j = 0; j < 3; ++j) { g1[i][j] = Z; g2[i][j] = Z; }
  float q2[3] = {0.f, 0.f, 0.f}, k2[3] = {0.f, 0.f, 0.f};
  float cn2[3] = {0.f, 0.f, 0.f}, qc[3] = {0.f, 0.f, 0.f};

  int sBase = split * 512;
  for (int chunk = 0; chunk < 8; ++chunk) {
    int sb = sBase + chunk * 64;
    const f16* qrow = qkvd + ((size_t)b * NS + sb + lane) * NC3 + h * 48;
    const f16* crow = cnf + ((size_t)b * NS + sb + lane) * NC + h * 48;
    f16x8 qv[6], kv[6], nv[6];
#pragma unroll
    for (int i = 0; i < 6; ++i) {
      qv[i] = *(const f16x8*)(qrow + i * 8);
      kv[i] = *(const f16x8*)(qrow + 192 + i * 8);
      nv[i] = *(const f16x8*)(crow + i * 8);
    }
    __syncthreads();                 // previous iter's frag reads done
#pragma unroll
    for (int i = 0; i < 6; ++i)
#pragma unroll
      for (int j = 0; j < 8; ++j) {
        int c = i * 8 + j;
        qT[c * 72 + lane] = qv[i][j];
        kT[c * 72 + lane] = kv[i][j];
        cT[c * 72 + lane] = nv[i][j];
      }
    __syncthreads();
#pragma unroll
    for (int kk = 0; kk < 2; ++kk) {
      int ko = kk * 32 + quad * 8;
      f16x8 bfr[3];
#pragma unroll
      for (int dt = 0; dt < 3; ++dt) {
        bfr[dt] = *(const f16x8*)(kT + (dt * 16 + l16) * 72 + ko);
#pragma unroll
        for (int j = 0; j < 8; ++j) { float kf = (float)bfr[dt][j]; k2[dt] += kf * kf; }
      }
#pragma unroll
      for (int ct = 0; ct < 3; ++ct) {
        f16x8 aq = *(const f16x8*)(qT + (ct * 16 + l16) * 72 + ko);
        f16x8 an = *(const f16x8*)(cT + (ct * 16 + l16) * 72 + ko);
#pragma unroll
        for (int j = 0; j < 8; ++j) {
          float qf = (float)aq[j], nf = (float)an[j];
          q2[ct] += qf * qf; cn2[ct] += nf * nf; qc[ct] += qf * nf;
        }
#pragma unroll
        for (int dt = 0; dt < 3; ++dt) {
          g1[ct][dt] = MFMA(aq, bfr[dt], g1[ct][dt]);
          g2[ct][dt] = MFMA(an, bfr[dt], g2[ct][dt]);
        }
      }
    }
  }
  // G partial write (coalesced, no atomics)
  size_t gbase = ((size_t)((b * NHD + h) * 32 + split)) * 2304;
#pragma unroll
  for (int ct = 0; ct < 3; ++ct)
#pragma unroll
    for (int dt = 0; dt < 3; ++dt)
#pragma unroll
      for (int r = 0; r < 4; ++r) {
        int c = ct * 16 + quad * 4 + r;
        int d = dt * 16 + l16;
        G1p[gbase + c * 48 + d] = g1[ct][dt][r];
        G2p[gbase + c * 48 + d] = g2[ct][dt][r];
      }
  // stats: reduce across quads (lanes l16, l16+16, l16+32, l16+48)
#pragma unroll
  for (int t = 0; t < 3; ++t) {
    q2[t] += __shfl_xor(q2[t], 16, 64);  q2[t] += __shfl_xor(q2[t], 32, 64);
    k2[t] += __shfl_xor(k2[t], 16, 64);  k2[t] += __shfl_xor(k2[t], 32, 64);
    cn2[t] += __shfl_xor(cn2[t], 16, 64); cn2[t] += __shfl_xor(cn2[t], 32, 64);
    qc[t] += __shfl_xor(qc[t], 16, 64);  qc[t] += __shfl_xor(qc[t], 32, 64);
  }
  if (lane < 16) {
#pragma unroll
    for (int ct = 0; ct < 3; ++ct) {
      int c = h * 48 + ct * 16 + lane;
      float* np = npart + (((size_t)(b * 32 + split)) * NC + c) * 4;
      np[0] = q2[ct]; np[1] = k2[ct]; np[2] = cn2[ct]; np[3] = qc[ct];
    }
  }
}

// ---------------------------------------------------------------------------
// E1b: norms[b][c][4] = sum over 32 splits of npart. 6144 threads, coalesced.
__global__ void k_e1b(const float* __restrict__ npart, float* __restrict__ norms)
{
  int idx = blockIdx.x * 256 + threadIdx.x;    // 6144
  int b = idx / 768;
  int cs = idx % 768;                          // c*4 + stat
  const float* p = npart + (size_t)b * 32 * 768 + cs;
  float s = 0.f;
#pragma unroll
  for (int sp = 0; sp < 32; ++sp) s += p[sp * 768];
  norms[idx] = s;
}

// ---------------------------------------------------------------------------
// E2b: G[bh][c][d] = sum over 32 splits of partials. 294912 threads, coalesced.
__global__ void k_e2b(const float* __restrict__ G1p, const float* __restrict__ G2p,
                      float* __restrict__ G1, float* __restrict__ G2)
{
  int idx = blockIdx.x * 256 + threadIdx.x;    // 294912
  int bh = idx / 2304;
  int cd = idx % 2304;
  const float* p1 = G1p + ((size_t)bh * 32) * 2304 + cd;
  const float* p2 = G2p + ((size_t)bh * 32) * 2304 + cd;
  float s1 = 0.f, s2 = 0.f;
#pragma unroll
  for (int sp = 0; sp < 32; ++sp) { s1 += p1[sp * 2304]; s2 += p2[sp * 2304]; }
  G1[idx] = s1;
  G2[idx] = s2;
}

// ---------------------------------------------------------------------------
// F1: logits + softmax -> attn[b][h][c][d] (fp32)
__global__ __launch_bounds__(64)
void k_f1(const float* __restrict__ G1, const float* __restrict__ G2,
          const float* __restrict__ norms, const float* __restrict__ temp,
          float* __restrict__ attn)
{
  __shared__ float S[48 * 48];
  int h = blockIdx.x & 3, b = blockIdx.x >> 2;
  int t = threadIdx.x;
  float T = temp[h];
  const float EPS = 1e-12f;
#pragma unroll
  for (int i = 0; i < 36; ++i) {
    int idx = i * 64 + t;
    int c = idx / 48, d = idx % 48;
    const float* np = norms + ((size_t)b * NC + h * 48 + c) * 4;
    float q2 = np[0], cn2 = np[2], qc = np[3];
    float nq = fmaxf(sqrtf(q2), EPS);
    float ncn = fmaxf(sqrtf(cn2), EPS);
    float k2 = norms[((size_t)b * NC + h * 48 + d) * 4 + 1];
    float nk = fmaxf(sqrtf(k2), EPS);
    float ss = q2 / (nq * nq) + 2.f * qc / (nq * ncn) + cn2 / (ncn * ncn);
    float nsum = fmaxf(sqrtf(fmaxf(ss, 0.f)), EPS);
    size_t go = (((size_t)(b * NHD + h) * 48 + c) * 48 + d);
    S[idx] = (G1[go] / nq + G2[go] / ncn) / (nsum * nk) * T;
  }
  __syncthreads();
  if (t < 48) {
    float mx = -1e30f;
    for (int d = 0; d < 48; ++d) mx = fmaxf(mx, S[t * 48 + d]);
    float sum = 0.f;
    for (int d = 0; d < 48; ++d) { float e = expf(S[t * 48 + d] - mx); S[t * 48 + d] = e; sum += e; }
    float inv = 1.f / sum;
    float* ap = attn + (((size_t)(b * NHD + h) * 48 + t) * 48);
    for (int d = 0; d < 48; ++d) ap[d] = S[t * 48 + d] * inv;
  }
}

// ---------------------------------------------------------------------------
// F2: Mcomb[b][co][dg] = sum_cl projw[co][h*48+cl] * attn[b][h][cl][dg%48]  (f16 out)
__global__ void k_f2(const float* __restrict__ attn, const float* __restrict__ projw,
                     f16* __restrict__ mcomb)
{
  int idx = blockIdx.x * 256 + threadIdx.x;   // 294912 exact
  int dg = idx % NC;
  int co = (idx / NC) % NC;
  int b = idx / (NC * NC);
  int h = dg / 48, dl = dg % 48;
  const float* pw = projw + (size_t)co * NC + h * 48;
  const float* at = attn + ((size_t)(b * NHD + h) * 48) * 48 + dl;
  float a = 0.f;
#pragma unroll
  for (int cl = 0; cl < 48; ++cl) a += pw[cl] * at[cl * 48];
  mcomb[idx] = (f16)a;
}

// ---------------------------------------------------------------------------
// G: out[b][co][s] = sum_dg mcomb[b][co][dg] * v[b][s][dg], fp32 out
__global__ __launch_bounds__(256, 2)
void k_gemm_out(const f16* __restrict__ mcomb, const f16* __restrict__ qkvd,
                float* __restrict__ out)
{
  __shared__ f16 At[64 * 32];
  __shared__ f16 Bt[256 * 32];
  const int tid = threadIdx.x;
  const int b = blockIdx.z;
  const int s0 = blockIdx.x * 256;
  const int m0 = blockIdx.y * 64;
  const int w = tid >> 6, lane = tid & 63, quad = lane >> 4, l16 = lane & 15;
  const f16* mcB = mcomb + (size_t)b * NC * NC;
  const f16* vB = qkvd + (size_t)b * NS * NC3 + 384;

  const f32x4 Z = {0.f, 0.f, 0.f, 0.f};
  f32x4 acc[4][4];
#pragma unroll
  for (int i = 0; i < 4; ++i)
#pragma unroll
    for (int j = 0; j < 4; ++j) acc[i][j] = Z;

  for (int kc = 0; kc < 6; ++kc) {
    const int k0 = kc * 32;
    {
      int rb = (w << 4) + (lane >> 2);
      int colb = k0 + ((((lane & 3) + (rb >> 2)) & 3) << 3);
      async16(mcB + (size_t)(m0 + rb) * NC + colb, At + (size_t)(w << 4) * 32);
    }
#pragma unroll
    for (int i = 0; i < 4; ++i) {
      int r = i * 64 + (w << 4) + (lane >> 2);
      int col = k0 + ((((lane & 3) + (r >> 2)) & 3) << 3);
      async16(vB + (size_t)(s0 + r) * NC3 + col, Bt + (size_t)(i * 64 + (w << 4)) * 32);
    }
    __syncthreads();
    f16x8 af[4];
#pragma unroll
    for (int mt = 0; mt < 4; ++mt) {
      int m = mt * 16 + l16;
      int p = (quad - (m >> 2)) & 3;
      af[mt] = *(const f16x8*)(At + m * 32 + p * 8);
    }
#pragma unroll
    for (int nt = 0; nt < 4; ++nt) {
      int n = w * 64 + nt * 16 + l16;
      int p = (quad - (n >> 2)) & 3;
      f16x8 bf = *(const f16x8*)(Bt + n * 32 + p * 8);
#pragma unroll
      for (int mt = 0; mt < 4; ++mt) acc[mt][nt] = MFMA(af[mt], bf, acc[mt][nt]);
    }
    __syncthreads();
  }
#pragma unroll
  for (int mt = 0; mt < 4; ++mt)
#pragma unroll
    for (int r = 0; r < 4; ++r) {
      int cog = m0 + mt * 16 + quad * 4 + r;
      float* o = out + ((size_t)b * NC + cog) * NS + s0 + w * 64;
#pragma unroll
      for (int nt = 0; nt < 4; ++nt) o[nt * 16 + l16] = acc[mt][nt][r];
    }
}

// ---------------------------------------------------------------------------
extern "C" void kernel_launch(void* const* d_in, const int* in_sizes, int n_in,
                              void* d_out, int out_size, void* d_ws, size_t ws_size,
                              hipStream_t stream) {
  const float* x   = (const float*)d_in[0];
  const float* cn  = (const float*)d_in[1];
  const float* w1  = (const float*)d_in[2];
  const float* w3  = (const float*)d_in[3];
  const float* wq  = (const float*)d_in[4];
  const float* wdw = (const float*)d_in[5];
  const float* wpj = (const float*)d_in[6];
  const float* tmp = (const float*)d_in[7];
  float* out = (float*)d_out;
  char* ws = (char*)d_ws;

  f16* x16    = (f16*)(ws + OFF_X16);
  f16* cn16   = (f16*)(ws + OFF_CN16);
  f16* qkv1p  = (f16*)(ws + OFF_CN16);   // overlay: cn16 dead after kernel A
  f16* cn1    = (f16*)(ws + OFF_CN1);
  f16* cnf    = (f16*)(ws + OFF_CNF);
  f16* qkvd   = (f16*)(ws + OFF_QKVD);
  float* norms = (float*)(ws + OFF_NORMS);
  float* G1    = (float*)(ws + OFF_G1);
  float* G2    = (float*)(ws + OFF_G2);
  f16* zpad   = (f16*)(ws + OFF_ZPAD);
  float* attn  = (float*)(ws + OFF_ATTN);
  f16* w116   = (f16*)(ws + OFF_W116);
  f16* wq16   = (f16*)(ws + OFF_WQ16);
  f16* w3p    = (f16*)(ws + OFF_W3P);
  f16* mcomb  = (f16*)(ws + OFF_MCOMB);
  f16* wdwT   = (f16*)(ws + OFF_WDWT);
  float* G1p   = (float*)(ws + OFF_G1P);   // overlays dead cn1
  float* G2p   = (float*)(ws + OFF_G2P);
  float* npart = (float*)(ws + OFF_NPART);

  // zero page for conv3 edge lanes (ws is re-poisoned before every launch)
  hipMemsetAsync(ws + OFF_ZPAD, 0, 1024, stream);

  k_wcast<<<1893, 256, 0, stream>>>(w1, wq, w3, wdw, w116, wq16, w3p, wdwT);
  k_cast_t<<<dim3(256, 3, 16), 256, 0, stream>>>(x, cn, x16, cn16);
  k_gemm_act<<<dim3(64, 3, 8), 256, 0, stream>>>(cn16, w116, cn1);
  k_conv3<<<dim3(64, 3, 8), 256, 0, stream>>>(cn1, w3p, cnf, zpad);
  for (int p = 0; p < 3; ++p) {
    k_gemm_act<<<dim3(64, 3, 8), 256, 0, stream>>>(x16, wq16 + p * 36864, qkv1p);
    k_dw<<<12288, 256, 0, stream>>>(qkv1p, wdwT, qkvd, p);
  }
  k_e2<<<1024, 64, 0, stream>>>(qkvd, cnf, G1p, G2p, npart);
  k_e1b<<<24, 256, 0, stream>>>(npart, norms);
  k_e2b<<<1152, 256, 0, stream>>>(G1p, G2p, G1, G2);
  k_f1<<<32, 64, 0, stream>>>(G1, G2, norms, tmp, attn);
  k_f2<<<1152, 256, 0, stream>>>(attn, wpj, mcomb);
  k_gemm_out<<<dim3(64, 3, 8), 256, 0, stream>>>(mcomb, qkvd, out);

  (void)in_sizes; (void)n_in; (void)out_size; (void)ws_size;
}